// Round 13
// baseline (618.550 us; speedup 1.0000x reference)
//
#include <hip/hip_runtime.h>
#include <hip/hip_bf16.h>
#include <math.h>

#define NS 255
#define NB 64
#define NE 200
#define NH 300
#define TS 2048          // shorts per 4KB tile (64 rows x 32 k)
#define HTS 1024         // shorts per half tile (32 rows)
#define NBLK 512

// ws layout (bytes):
//  HbfT  [255][10][TS] bf16 tiled/swizzled  @ 0           (10,444,800)
//  Cf16  [255][10][TS] fp16 tiled/swizzled  @ 10,444,800  (10,444,800)
//  AembT [255][7][TS] bf16 tiled/swizzled   @ 20,889,600  ( 7,311,360)
//  BW    [4][5][17][TS] bf16 tiled/swizzled @ 28,200,960  ( 1,392,640)
//  bar   [32] int barrier counters          @ 29,593,600  (       128)

typedef __attribute__((ext_vector_type(8))) short short8;
typedef __attribute__((ext_vector_type(4))) float f32x4;

__device__ __forceinline__ float sigmoidf_(float x) { return 1.0f / (1.0f + __expf(-x)); }
__device__ __forceinline__ unsigned short f2bf(float v) {
    union { __hip_bfloat16 b; unsigned short u; } cv; cv.b = __float2bfloat16(v); return cv.u;
}
__device__ __forceinline__ float bf2f(unsigned short u) {
    union { unsigned short u; __hip_bfloat16 b; } cv; cv.u = u; return __bfloat162float(cv.b);
}
__device__ __forceinline__ unsigned short f2h(float v) {
    union { _Float16 h; unsigned short u; } cv; cv.h = (_Float16)v; return cv.u;
}
__device__ __forceinline__ float h2f(unsigned short u) {
    union { unsigned short u; _Float16 h; } cv; cv.u = u; return (float)cv.h;
}
__device__ __forceinline__ int swz(int row, int kk) {
    int g = (kk >> 3) ^ ((row >> 1) & 3);
    return ((row << 2) + g) * 8 + (kk & 7);
}

// Two-phase leader-flush grid barrier.
// Phase 1: every block arrives at c1 (its writes are quiesced in dirty L2 --
// __syncthreads drains vmcnt; NO fence, so no staggered re-flush, R10's bug).
// Phase 2: leader blocks 0..7 (one per XCD under bid&7 round-robin) wait for
// full arrival, then issue ONE agent-release (buffer_wbl2 flushes the whole
// shared per-XCD L2, covering all co-located blocks' lines, exactly-once
// dirty), then bump c2. Everyone proceeds at c2==8. Flushed lines stay
// CLEAN-RESIDENT -> same-XCD consumers get L2 hits next level.
// No-hang: c2 counts 8 leader *blocks* regardless of physical placement;
// co-residency of 512 blocks proven in R10 (occ 29.6%).
__device__ __forceinline__ void gbar(int* c1, int* c2, int tid, int bid) {
    __syncthreads();
    if (tid == 0) {
        __hip_atomic_fetch_add(c1, 1, __ATOMIC_RELAXED, __HIP_MEMORY_SCOPE_AGENT);
        if (bid < 8) {
            while (__hip_atomic_load(c1, __ATOMIC_RELAXED, __HIP_MEMORY_SCOPE_AGENT) < NBLK)
                __builtin_amdgcn_s_sleep(2);
            __builtin_amdgcn_fence(__ATOMIC_RELEASE, "agent");   // wbl2 + wait
            __hip_atomic_fetch_add(c2, 1, __ATOMIC_RELAXED, __HIP_MEMORY_SCOPE_AGENT);
        }
        while (__hip_atomic_load(c2, __ATOMIC_RELAXED, __HIP_MEMORY_SCOPE_AGENT) < 8)
            __builtin_amdgcn_s_sleep(2);
    }
    __syncthreads();
}

// chunk loop, 32-row half: A frags 2, B frags 4, 8 MFMA; A-stride templated
template<int NCH, int SA>
__device__ __forceinline__ void gemm2(f32x4 acc[4][2],
    const unsigned short* __restrict__ A, const unsigned short* __restrict__ B)
{
#pragma unroll
    for (int c = 0; c < NCH; ++c) {
        const unsigned short* At = A + c * SA;
        const unsigned short* Bt = B + c * TS;
        short8 a0 = *(const short8*)(At);
        short8 a1 = *(const short8*)(At + 512);
#pragma unroll
        for (int t = 0; t < 4; ++t) {
            short8 b = *(const short8*)(Bt + t * 512);
            acc[t][0] = __builtin_amdgcn_mfma_f32_16x16x32_bf16(a0, b, acc[t][0], 0, 0, 0);
            acc[t][1] = __builtin_amdgcn_mfma_f32_16x16x32_bf16(a1, b, acc[t][1], 0, 0, 0);
        }
    }
}
// full-M chunk loop (leaf): A frags 4, 16 MFMA
template<int NCH>
__device__ __forceinline__ void gemm_f(f32x4 acc[4][4],
    const unsigned short* __restrict__ A, const unsigned short* __restrict__ B)
{
#pragma unroll
    for (int c = 0; c < NCH; ++c) {
        const unsigned short* At = A + c * TS;
        const unsigned short* Bt = B + c * TS;
        short8 a0 = *(const short8*)(At);
        short8 a1 = *(const short8*)(At + 512);
        short8 a2 = *(const short8*)(At + 1024);
        short8 a3 = *(const short8*)(At + 1536);
#pragma unroll
        for (int t = 0; t < 4; ++t) {
            short8 b = *(const short8*)(Bt + t * 512);
            acc[t][0] = __builtin_amdgcn_mfma_f32_16x16x32_bf16(a0, b, acc[t][0], 0, 0, 0);
            acc[t][1] = __builtin_amdgcn_mfma_f32_16x16x32_bf16(a1, b, acc[t][1], 0, 0, 0);
            acc[t][2] = __builtin_amdgcn_mfma_f32_16x16x32_bf16(a2, b, acc[t][2], 0, 0, 0);
            acc[t][3] = __builtin_amdgcn_mfma_f32_16x16x32_bf16(a3, b, acc[t][3], 0, 0, 0);
        }
    }
}

// internal node task (p, strip s, half): R12-proven burst-staged body.
__device__ __forceinline__ void do_internal(unsigned short* sm,
    int p, int s, int half, int tid,
    const unsigned short* __restrict__ AembT, const unsigned short* __restrict__ BW,
    const float* __restrict__ b_iou, const float* __restrict__ b_f,
    unsigned short* __restrict__ HbfT, unsigned short* __restrict__ Cg)
{
    __syncthreads();   // protect LDS reuse across back-to-back tasks
    int w = tid >> 6, lane = tid & 63, ln = lane & 15, quad = lane >> 4;
    int l = 2 * p + 1, r = 2 * p + 2;
    int bsel = (w < 4) ? w : 3;
    int gq = (quad ^ ((ln >> 1) & 3)) * 8;
    int offA = (half * 32 + ln) * 32 + gq;
    int offL = ln * 32 + gq;
    int offB = ln * 32 + gq;

    // burst-stage: slots 0..9 Hl, 10..19 Hr, 20..21 Cl(2s,2s+1), 22..23 Cr
    for (int idx = w; idx < 24; idx += 5) {
        const unsigned short* gsrc;
        if (idx < 20) {
            int node = (idx < 10) ? l : r;
            int tt = (idx < 10) ? idx : idx - 10;
            gsrc = HbfT + ((size_t)node * 10 + tt) * TS + half * HTS;
        } else {
            int ii = idx - 20;
            int node = (ii < 2) ? l : r;
            gsrc = Cg + ((size_t)node * 10 + 2 * s + (ii & 1)) * TS + half * HTS;
        }
        unsigned short* ldst = sm + idx * HTS;
#pragma unroll
        for (int u = 0; u < 2; ++u)
            __builtin_amdgcn_global_load_lds(
                (const __attribute__((address_space(1))) unsigned short*)(gsrc + u * 512 + lane * 8),
                (__attribute__((address_space(3))) unsigned short*)(ldst + u * 512 + lane * 8),
                16, 0, 0);
    }

    f32x4 acc[4][2];
#pragma unroll
    for (int t = 0; t < 4; ++t)
#pragma unroll
        for (int q = 0; q < 2; ++q) acc[t][q] = (f32x4){0.f, 0.f, 0.f, 0.f};

    const unsigned short* Bsrc = BW + (size_t)(bsel * 5 + s) * 17 * TS;
    const unsigned short* Ae = AembT + (size_t)p * 7 * TS;
    gemm2<7, TS>(acc, Ae + offA, Bsrc + offB);

    __syncthreads();   // vmcnt(0): staging complete

    const unsigned short* BH = Bsrc + 7 * TS + offB;
    if (w < 3) {
        gemm2<10, HTS>(acc, sm + offL, BH);
        gemm2<10, HTS>(acc, sm + 10 * HTS + offL, BH);
    } else if (w == 3) {
        gemm2<10, HTS>(acc, sm + offL, BH);
    } else {
        gemm2<10, HTS>(acc, sm + 10 * HTS + offL, BH);
    }

    float* smf = (float*)sm;    // aliases slots 0..5 (A consumed); C in 20..23
    for (int t = 0; t < 4; ++t) {
        __syncthreads();
#pragma unroll
        for (int ms = 0; ms < 2; ++ms)
#pragma unroll
            for (int rr = 0; rr < 4; ++rr)
                smf[w * 544 + (ms * 16 + quad * 4 + rr) * 17 + ln] = acc[t][ms][rr];
        __syncthreads();
        for (int idx2 = tid; idx2 < 512; idx2 += 320) {
            int mm = idx2 >> 4, n = idx2 & 15;
            int gm = half * 32 + mm;
            int jj = s * 64 + t * 16 + n;
            bool ok = jj < NH;
            float pi = smf[0 * 544 + mm * 17 + n] + (ok ? b_iou[jj] : 0.f);
            float po = smf[1 * 544 + mm * 17 + n] + (ok ? b_iou[NH + jj] : 0.f);
            float pu = smf[2 * 544 + mm * 17 + n] + (ok ? b_iou[2 * NH + jj] : 0.f);
            float bj = ok ? b_f[jj] : 0.f;
            float fl = sigmoidf_(smf[3 * 544 + mm * 17 + n] + bj);
            float fr = sigmoidf_(smf[4 * 544 + mm * 17 + n] + bj);
            int xr = (mm >> 1) & 3;
            int cel = (mm * 4 + ((((t & 1) * 2) + (n >> 3)) ^ xr)) * 8 + (n & 7);
            int ts2 = t >> 1;
            float cl = h2f(sm[(20 + ts2) * HTS + cel]);
            float cr = h2f(sm[(22 + ts2) * HTS + cel]);
            float cc = sigmoidf_(pi) * tanhf(pu) + fl * cl + fr * cr;
            float hh = sigmoidf_(po) * tanhf(cc);
            size_t tbase = ((size_t)p * 10 + (jj >> 5)) * TS + swz(gm, jj & 31);
            if (ok) Cg[tbase] = f2h(cc);
            HbfT[tbase] = ok ? f2bf(hh) : (unsigned short)0;
        }
    }
}

// leaf task (p, strip s): full 64-M, waves 0..2 = i/o/u (R12-proven)
__device__ __forceinline__ void do_leaf(unsigned short* sm, int p, int s,
    int tid, const unsigned short* __restrict__ AembT,
    const unsigned short* __restrict__ BW, const float* __restrict__ b_iou,
    unsigned short* __restrict__ HbfT, unsigned short* __restrict__ Cg)
{
    __syncthreads();
    int w = tid >> 6, lane = tid & 63, ln = lane & 15, quad = lane >> 4;
    int off = ln * 32 + (quad ^ ((ln >> 1) & 3)) * 8;

    f32x4 acc[4][4];
#pragma unroll
    for (int t = 0; t < 4; ++t)
#pragma unroll
        for (int q = 0; q < 4; ++q) acc[t][q] = (f32x4){0.f, 0.f, 0.f, 0.f};

    if (w < 3) {
        const unsigned short* Bsrc = BW + (size_t)(w * 5 + s) * 17 * TS;
        const unsigned short* Ae = AembT + (size_t)p * 7 * TS;
        gemm_f<7>(acc, Ae + off, Bsrc + off);
    }

    float* tile = (float*)sm;   // [3][64][16] = 12 KB
    for (int t = 0; t < 4; ++t) {
        __syncthreads();
        if (w < 3)
#pragma unroll
            for (int ms = 0; ms < 4; ++ms)
#pragma unroll
                for (int rr = 0; rr < 4; ++rr)
                    tile[(w * 64 + ms * 16 + quad * 4 + rr) * 16 + ln] = acc[t][ms][rr];
        __syncthreads();
        for (int idx2 = tid; idx2 < 1024; idx2 += 320) {
            int mm = idx2 >> 4, n = idx2 & 15;
            int jj = s * 64 + t * 16 + n;
            bool ok = jj < NH;
            float pi = tile[(0 * 64 + mm) * 16 + n] + (ok ? b_iou[jj] : 0.f);
            float po = tile[(1 * 64 + mm) * 16 + n] + (ok ? b_iou[NH + jj] : 0.f);
            float pu = tile[(2 * 64 + mm) * 16 + n] + (ok ? b_iou[2 * NH + jj] : 0.f);
            float cc = sigmoidf_(pi) * tanhf(pu);
            float hh = sigmoidf_(po) * tanhf(cc);
            size_t tbase = ((size_t)p * 10 + (jj >> 5)) * TS + swz(mm, jj & 31);
            if (ok) Cg[tbase] = f2h(cc);
            HbfT[tbase] = ok ? f2bf(hh) : (unsigned short)0;
        }
    }
}

// ---------------- single persistent kernel (plain launch) -------------------
__global__ __launch_bounds__(320, 4) void fused_kernel(
    const float* __restrict__ U_iou, const float* __restrict__ U_f,
    const float* __restrict__ W_iou, const float* __restrict__ W_f,
    const float* __restrict__ embed, const int* __restrict__ x,
    const float* __restrict__ b_iou, const float* __restrict__ b_f,
    const float* __restrict__ W_out, const float* __restrict__ b_out,
    unsigned short* __restrict__ BW, unsigned short* __restrict__ AembT,
    unsigned short* __restrict__ HbfT, unsigned short* __restrict__ Cg,
    float* __restrict__ out, int* __restrict__ bar)
{
    __shared__ unsigned short sm[24 * HTS];   // 48 KB
    int bid = blockIdx.x;
    int tid = threadIdx.x;

    // ---- phase 0: prep (R12-proven granule layout, plain cached stores) ----
    {
        const int gBW = 4 * 5 * 17 * 256;
        const int gAe = NS * 7 * 256;
        int total = gBW + gAe;
        int stride = NBLK * 320;
        for (int gi = bid * 320 + tid; gi < total; gi += stride) {
            unsigned short st[8];
            if (gi < gBW) {
                int gg = gi & 255, tile = gi >> 8;
                int row = gg >> 2, pos = gg & 3;
                int kk0 = (pos ^ ((row >> 1) & 3)) << 3;
                int c = tile % 17, t2 = tile / 17;
                int s = t2 % 5, g4 = t2 / 5;
                int j = s * 64 + row;
#pragma unroll
                for (int u = 0; u < 8; ++u) {
                    int kk = kk0 + u; float v = 0.f;
                    if (c < 7) {
                        int k = c * 32 + kk;
                        if (j < NH && k < NE)
                            v = (g4 < 3) ? W_iou[k * 900 + g4 * NH + j] : W_f[k * NH + j];
                    } else {
                        int k = (c - 7) * 32 + kk;
                        if (j < NH && k < NH)
                            v = (g4 < 3) ? U_iou[k * 900 + g4 * NH + j] : U_f[k * NH + j];
                    }
                    st[u] = f2bf(v);
                }
                *(short8*)(BW + (size_t)tile * TS + (row * 4 + pos) * 8) = *(short8*)st;
            } else {
                int gi2 = gi - gBW;
                int gg = gi2 & 255, tile = gi2 >> 8;
                int row = gg >> 2, pos = gg & 3;
                int kk0 = (pos ^ ((row >> 1) & 3)) << 3;
                int c = tile % 7, node = tile / 7;
                int k0 = c * 32 + kk0;
                const float* er = embed + (size_t)x[node * NB + row] * NE;
#pragma unroll
                for (int u = 0; u < 8; ++u)
                    st[u] = (k0 + u < NE) ? f2bf(er[k0 + u]) : (unsigned short)0;
                *(short8*)(AembT + (size_t)tile * TS + (row * 4 + pos) * 8) = *(short8*)st;
            }
        }
    }
    gbar(bar + 0, bar + 1, tid, bid);

    int xcd = bid & 7, slot = bid >> 3;

    // ---- leaf d=7: per-xcd 16 nodes x 5 strips = 80 tasks ----
    for (int t = slot; t < 80; t += 64)
        do_leaf(sm, 127 + xcd * 16 + (t & 15), t >> 4, tid, AembT, BW, b_iou, HbfT, Cg);
    gbar(bar + 2, bar + 3, tid, bid);

    // ---- levels 6..3: per-xcd m nodes x 5 strips x 2 halves (subtree map:
    // children of (xcd,o) are (xcd,2o),(xcd,2o+1) -> same-XCD L2 hits) ----
    int bi = 4;
    for (int d = 6; d >= 3; --d) {
        int base = (1 << d) - 1;
        int m = 1 << (d - 3);
        int T = m * 10;
        for (int t = slot; t < T; t += 64) {
            int o = t % m, rest = t / m;
            do_internal(sm, base + xcd * m + o, rest % 5, rest / 5,
                        tid, AembT, BW, b_iou, b_f, HbfT, Cg);
        }
        gbar(bar + bi, bar + bi + 1, tid, bid); bi += 2;
    }
    // ---- levels 2..0: node idx on xcd = idx<<(3-d), 10 tasks at slots 0..9
    for (int d = 2; d >= 0; --d) {
        int n = 1 << d, sh = 3 - d;
        if ((xcd & ((1 << sh) - 1)) == 0 && (xcd >> sh) < n && slot < 10)
            do_internal(sm, n - 1 + (xcd >> sh), slot % 5, slot / 5,
                        tid, AembT, BW, b_iou, b_f, HbfT, Cg);
        gbar(bar + bi, bar + bi + 1, tid, bid); bi += 2;
    }

    // ---- out: root -> logits -> log_softmax (root on XCD0 = bid 0) ----
    if (bid == 0 && tid < NB) {
        int b = tid;
        float l0 = 0.f, l1 = 0.f;
#pragma unroll 4
        for (int k = 0; k < NH; ++k) {
            float hk = bf2f(HbfT[(size_t)(k >> 5) * TS + swz(b, k & 31)]);
            l0 += hk * W_out[k * 2];
            l1 += hk * W_out[k * 2 + 1];
        }
        l0 += b_out[0];
        l1 += b_out[1];
        float mx = fmaxf(l0, l1);
        float lse = mx + logf(__expf(l0 - mx) + __expf(l1 - mx));
        out[b * 2 + 0] = l0 - lse;
        out[b * 2 + 1] = l1 - lse;
    }
}

extern "C" void kernel_launch(void* const* d_in, const int* in_sizes, int n_in,
                              void* d_out, int out_size, void* d_ws, size_t ws_size,
                              hipStream_t stream)
{
    const int*   x     = (const int*)d_in[0];
    const float* embed = (const float*)d_in[3];
    const float* W_iou = (const float*)d_in[4];
    const float* U_iou = (const float*)d_in[5];
    const float* b_iou = (const float*)d_in[6];
    const float* W_f   = (const float*)d_in[7];
    const float* U_f   = (const float*)d_in[8];
    const float* b_f   = (const float*)d_in[9];
    const float* W_out = (const float*)d_in[10];
    const float* b_out = (const float*)d_in[11];

    char* ws = (char*)d_ws;
    unsigned short* HbfT  = (unsigned short*)(ws + 0);
    unsigned short* Cg    = (unsigned short*)(ws + 10444800);
    unsigned short* AembT = (unsigned short*)(ws + 20889600);
    unsigned short* BW    = (unsigned short*)(ws + 28200960);
    int*            bar   = (int*)(ws + 29593600);

    hipMemsetAsync(bar, 0, 128, stream);
    fused_kernel<<<NBLK, 320, 0, stream>>>(U_iou, U_f, W_iou, W_f, embed, x,
                                           b_iou, b_f, W_out, b_out,
                                           BW, AembT, HbfT, Cg,
                                           (float*)d_out, bar);
}

// Round 14
// 304.579 us; speedup vs baseline: 2.0308x; 2.0308x over previous
//
#include <hip/hip_runtime.h>
#include <hip/hip_bf16.h>
#include <math.h>

#define NS 255
#define NB 64
#define NE 200
#define NH 300
#define TS 2048          // shorts per 4KB tile (64 rows x 32 k)
#define HTS 1024         // shorts per half tile (32 rows)

// ws layout (bytes):
//  HbfT  [255][10][TS] bf16 tiled/swizzled  @ 0           (10,444,800)
//  Cf16  [255][10][TS] fp16 tiled/swizzled  @ 10,444,800  (10,444,800)
//  (gap: former AembT region, unused)
//  BW    [4][5][17][TS] bf16 tiled/swizzled @ 28,200,960  ( 1,392,640)
//  bar   [16] int tail-barrier counters     @ 29,593,600  (        64)

typedef __attribute__((ext_vector_type(8))) short short8;
typedef __attribute__((ext_vector_type(4))) float f32x4;

__device__ __forceinline__ float sigmoidf_(float x) { return 1.0f / (1.0f + __expf(-x)); }
__device__ __forceinline__ unsigned short f2bf(float v) {
    union { __hip_bfloat16 b; unsigned short u; } cv; cv.b = __float2bfloat16(v); return cv.u;
}
__device__ __forceinline__ float bf2f(unsigned short u) {
    union { unsigned short u; __hip_bfloat16 b; } cv; cv.u = u; return __bfloat162float(cv.b);
}
__device__ __forceinline__ unsigned short f2h(float v) {
    union { _Float16 h; unsigned short u; } cv; cv.h = (_Float16)v; return cv.u;
}
__device__ __forceinline__ float h2f(unsigned short u) {
    union { unsigned short u; _Float16 h; } cv; cv.u = u; return (float)cv.h;
}
__device__ __forceinline__ int swz(int row, int kk) {
    int g = (kk >> 3) ^ ((row >> 1) & 3);
    return ((row << 2) + g) * 8 + (kk & 7);
}
// sc1 write-through store (R11-proven correct for cross-block visibility)
__device__ __forceinline__ void st_u16(unsigned short* p, unsigned short v) {
    __hip_atomic_store(p, v, __ATOMIC_RELAXED, __HIP_MEMORY_SCOPE_AGENT);
}

// ---------------- prep: weights only (Aemb eliminated) ----------------------
__global__ __launch_bounds__(256) void prep_kernel(
    const float* __restrict__ U_iou, const float* __restrict__ U_f,
    const float* __restrict__ W_iou, const float* __restrict__ W_f,
    unsigned short* __restrict__ BW)
{
    int gi = blockIdx.x * blockDim.x + threadIdx.x;
    if (gi >= 4 * 5 * 17 * 256) return;
    unsigned short st[8];
    int gg = gi & 255, tile = gi >> 8;
    int row = gg >> 2, pos = gg & 3;
    int kk0 = (pos ^ ((row >> 1) & 3)) << 3;
    int c = tile % 17, t2 = tile / 17;
    int s = t2 % 5, g4 = t2 / 5;
    int j = s * 64 + row;
#pragma unroll
    for (int u = 0; u < 8; ++u) {
        int kk = kk0 + u; float v = 0.f;
        if (c < 7) {
            int k = c * 32 + kk;
            if (j < NH && k < NE)
                v = (g4 < 3) ? W_iou[k * 900 + g4 * NH + j] : W_f[k * NH + j];
        } else {
            int k = (c - 7) * 32 + kk;
            if (j < NH && k < NH)
                v = (g4 < 3) ? U_iou[k * 900 + g4 * NH + j] : U_f[k * NH + j];
        }
        st[u] = f2bf(v);
    }
    *(short8*)(BW + (size_t)tile * TS + (row * 4 + pos) * 8) = *(short8*)st;
}

// load 8 fp32 emb values at k0 and convert to a bf16 A-fragment (k>=NE -> 0).
// k0 = c*32 + quad*8 reproduces the tiled layout's lane->k mapping exactly.
__device__ __forceinline__ short8 ldcvt(const float* __restrict__ e, int k0) {
    short8 r = (short8)(short)0;
    if (k0 < NE) {
        const float* p = e + k0;   // 32B-aligned: row base 800B, k0 mult of 8
#pragma unroll
        for (int u = 0; u < 8; ++u)
            ((unsigned short*)&r)[u] = f2bf(p[u]);
    }
    return r;
}

// emb@W contribution, half-M (2 A-frags): direct fp32 loads + cvt
__device__ __forceinline__ void gemm_emb2(f32x4 acc[4][2],
    const float* __restrict__ e0, const float* __restrict__ e1,
    const unsigned short* __restrict__ B, int quad)
{
#pragma unroll
    for (int c = 0; c < 7; ++c) {
        int k0 = c * 32 + quad * 8;
        short8 a0 = ldcvt(e0, k0);
        short8 a1 = ldcvt(e1, k0);
        const unsigned short* Bt = B + c * TS;
#pragma unroll
        for (int t = 0; t < 4; ++t) {
            short8 b = *(const short8*)(Bt + t * 512);
            acc[t][0] = __builtin_amdgcn_mfma_f32_16x16x32_bf16(a0, b, acc[t][0], 0, 0, 0);
            acc[t][1] = __builtin_amdgcn_mfma_f32_16x16x32_bf16(a1, b, acc[t][1], 0, 0, 0);
        }
    }
}
// emb@W contribution, full-M (4 A-frags, leaf)
__device__ __forceinline__ void gemm_emb4(f32x4 acc[4][4],
    const float* __restrict__ e0, const float* __restrict__ e1,
    const float* __restrict__ e2, const float* __restrict__ e3,
    const unsigned short* __restrict__ B, int quad)
{
#pragma unroll
    for (int c = 0; c < 7; ++c) {
        int k0 = c * 32 + quad * 8;
        short8 a0 = ldcvt(e0, k0);
        short8 a1 = ldcvt(e1, k0);
        short8 a2 = ldcvt(e2, k0);
        short8 a3 = ldcvt(e3, k0);
        const unsigned short* Bt = B + c * TS;
#pragma unroll
        for (int t = 0; t < 4; ++t) {
            short8 b = *(const short8*)(Bt + t * 512);
            acc[t][0] = __builtin_amdgcn_mfma_f32_16x16x32_bf16(a0, b, acc[t][0], 0, 0, 0);
            acc[t][1] = __builtin_amdgcn_mfma_f32_16x16x32_bf16(a1, b, acc[t][1], 0, 0, 0);
            acc[t][2] = __builtin_amdgcn_mfma_f32_16x16x32_bf16(a2, b, acc[t][2], 0, 0, 0);
            acc[t][3] = __builtin_amdgcn_mfma_f32_16x16x32_bf16(a3, b, acc[t][3], 0, 0, 0);
        }
    }
}
// H-part chunk loop from LDS (R12-proven)
template<int NCH>
__device__ __forceinline__ void gemm_h(f32x4 acc[4][2],
    const unsigned short* __restrict__ A, const unsigned short* __restrict__ B)
{
#pragma unroll
    for (int c = 0; c < NCH; ++c) {
        const unsigned short* At = A + c * HTS;
        const unsigned short* Bt = B + c * TS;
        short8 a0 = *(const short8*)(At);
        short8 a1 = *(const short8*)(At + 512);
#pragma unroll
        for (int t = 0; t < 4; ++t) {
            short8 b = *(const short8*)(Bt + t * 512);
            acc[t][0] = __builtin_amdgcn_mfma_f32_16x16x32_bf16(a0, b, acc[t][0], 0, 0, 0);
            acc[t][1] = __builtin_amdgcn_mfma_f32_16x16x32_bf16(a1, b, acc[t][1], 0, 0, 0);
        }
    }
}

// internal node task (p, strip s, half): R12-proven burst-staged body.
// devst=1 -> sc1 write-through H/C stores (tail kernel cross-level visibility)
__device__ __forceinline__ void internal_body(unsigned short* sm,
    int p, int s, int half, int tid,
    const int* __restrict__ x, const float* __restrict__ embed,
    const unsigned short* __restrict__ BW,
    const float* __restrict__ b_iou, const float* __restrict__ b_f,
    unsigned short* __restrict__ HbfT, unsigned short* __restrict__ Cg, int devst)
{
    __syncthreads();   // protect LDS reuse across back-to-back tasks
    int w = tid >> 6, lane = tid & 63, ln = lane & 15, quad = lane >> 4;
    int l = 2 * p + 1, r = 2 * p + 2;
    int bsel = (w < 4) ? w : 3;
    int gq = (quad ^ ((ln >> 1) & 3)) * 8;
    int offL = ln * 32 + gq;
    int offB = ln * 32 + gq;

    // burst-stage children: slots 0..9 Hl, 10..19 Hr, 20..21 Cl, 22..23 Cr
    for (int idx = w; idx < 24; idx += 5) {
        const unsigned short* gsrc;
        if (idx < 20) {
            int node = (idx < 10) ? l : r;
            int tt = (idx < 10) ? idx : idx - 10;
            gsrc = HbfT + ((size_t)node * 10 + tt) * TS + half * HTS;
        } else {
            int ii = idx - 20;
            int node = (ii < 2) ? l : r;
            gsrc = Cg + ((size_t)node * 10 + 2 * s + (ii & 1)) * TS + half * HTS;
        }
        unsigned short* ldst = sm + idx * HTS;
#pragma unroll
        for (int u = 0; u < 2; ++u)
            __builtin_amdgcn_global_load_lds(
                (const __attribute__((address_space(1))) unsigned short*)(gsrc + u * 512 + lane * 8),
                (__attribute__((address_space(3))) unsigned short*)(ldst + u * 512 + lane * 8),
                16, 0, 0);
    }

    f32x4 acc[4][2];
#pragma unroll
    for (int t = 0; t < 4; ++t)
#pragma unroll
        for (int q = 0; q < 2; ++q) acc[t][q] = (f32x4){0.f, 0.f, 0.f, 0.f};

    // emb contribution (direct fp32 gather) while LDS DMA is in flight
    const unsigned short* Bsrc = BW + (size_t)(bsel * 5 + s) * 17 * TS;
    int row0 = half * 32 + ln;
    const float* e0 = embed + (size_t)x[p * NB + row0] * NE;
    const float* e1 = embed + (size_t)x[p * NB + row0 + 16] * NE;
    gemm_emb2(acc, e0, e1, Bsrc + offB, quad);

    __syncthreads();   // vmcnt(0): staging complete

    const unsigned short* BH = Bsrc + 7 * TS + offB;
    if (w < 3) {
        gemm_h<10>(acc, sm + offL, BH);
        gemm_h<10>(acc, sm + 10 * HTS + offL, BH);
    } else if (w == 3) {
        gemm_h<10>(acc, sm + offL, BH);
    } else {
        gemm_h<10>(acc, sm + 10 * HTS + offL, BH);
    }

    float* smf = (float*)sm;    // aliases slots 0..5 (A consumed); C in 20..23
    for (int t = 0; t < 4; ++t) {
        __syncthreads();
#pragma unroll
        for (int ms = 0; ms < 2; ++ms)
#pragma unroll
            for (int rr = 0; rr < 4; ++rr)
                smf[w * 544 + (ms * 16 + quad * 4 + rr) * 17 + ln] = acc[t][ms][rr];
        __syncthreads();
        for (int idx2 = tid; idx2 < 512; idx2 += 320) {
            int mm = idx2 >> 4, n = idx2 & 15;
            int gm = half * 32 + mm;
            int jj = s * 64 + t * 16 + n;
            bool ok = jj < NH;
            float pi = smf[0 * 544 + mm * 17 + n] + (ok ? b_iou[jj] : 0.f);
            float po = smf[1 * 544 + mm * 17 + n] + (ok ? b_iou[NH + jj] : 0.f);
            float pu = smf[2 * 544 + mm * 17 + n] + (ok ? b_iou[2 * NH + jj] : 0.f);
            float bj = ok ? b_f[jj] : 0.f;
            float fl = sigmoidf_(smf[3 * 544 + mm * 17 + n] + bj);
            float fr = sigmoidf_(smf[4 * 544 + mm * 17 + n] + bj);
            int xr = (mm >> 1) & 3;
            int cel = (mm * 4 + ((((t & 1) * 2) + (n >> 3)) ^ xr)) * 8 + (n & 7);
            int ts2 = t >> 1;
            float cl = h2f(sm[(20 + ts2) * HTS + cel]);
            float cr = h2f(sm[(22 + ts2) * HTS + cel]);
            float cc = sigmoidf_(pi) * tanhf(pu) + fl * cl + fr * cr;
            float hh = sigmoidf_(po) * tanhf(cc);
            size_t tbase = ((size_t)p * 10 + (jj >> 5)) * TS + swz(gm, jj & 31);
            unsigned short cv = f2h(cc);
            unsigned short hv = ok ? f2bf(hh) : (unsigned short)0;
            if (devst) {
                if (ok) st_u16(&Cg[tbase], cv);
                st_u16(&HbfT[tbase], hv);
            } else {
                if (ok) Cg[tbase] = cv;
                HbfT[tbase] = hv;
            }
        }
    }
}

// ---------------- internal levels 6..5 (separate dispatches) ----------------
__global__ __launch_bounds__(320) void level_kernel(
    const int* __restrict__ x, const float* __restrict__ embed,
    const unsigned short* __restrict__ BW,
    const float* __restrict__ b_iou, const float* __restrict__ b_f,
    unsigned short* __restrict__ HbfT, unsigned short* __restrict__ Cg,
    int base, int m)
{
    __shared__ unsigned short sm[24 * HTS];   // 48 KB
    int bid = blockIdx.x;
    int xcd = bid & 7, idx = bid >> 3;
    int o = idx % m, rest = idx / m;
    int p = base + xcd * m + o;
    internal_body(sm, p, rest % 5, rest / 5, threadIdx.x,
                  x, embed, BW, b_iou, b_f, HbfT, Cg, 0);
}

// ---------------- leaf level: 3 waves, direct-emb gather --------------------
__global__ __launch_bounds__(192) void leaf_kernel(
    const int* __restrict__ x, const float* __restrict__ embed,
    const unsigned short* __restrict__ BW, const float* __restrict__ b_iou,
    unsigned short* __restrict__ HbfT, unsigned short* __restrict__ Cg)
{
    int bid = blockIdx.x;
    int xcd = bid & 7, idx = bid >> 3;
    int o = idx % 16, s = idx / 16;
    int p = 127 + xcd * 16 + o;
    int tid = threadIdx.x;
    int w = tid >> 6, lane = tid & 63, ln = lane & 15, quad = lane >> 4;
    int offB = ln * 32 + (quad ^ ((ln >> 1) & 3)) * 8;

    const unsigned short* Bsrc = BW + (size_t)(w * 5 + s) * 17 * TS;
    const float* e0 = embed + (size_t)x[p * NB + ln] * NE;
    const float* e1 = embed + (size_t)x[p * NB + ln + 16] * NE;
    const float* e2 = embed + (size_t)x[p * NB + ln + 32] * NE;
    const float* e3 = embed + (size_t)x[p * NB + ln + 48] * NE;

    f32x4 acc[4][4];
#pragma unroll
    for (int t = 0; t < 4; ++t)
#pragma unroll
        for (int q = 0; q < 4; ++q) acc[t][q] = (f32x4){0.f, 0.f, 0.f, 0.f};

    gemm_emb4(acc, e0, e1, e2, e3, Bsrc + offB, quad);

    __shared__ float tile[3][64][16];   // 12 KB
    for (int t = 0; t < 4; ++t) {
        __syncthreads();
#pragma unroll
        for (int ms = 0; ms < 4; ++ms)
#pragma unroll
            for (int rr = 0; rr < 4; ++rr)
                tile[w][ms * 16 + quad * 4 + rr][ln] = acc[t][ms][rr];
        __syncthreads();
        for (int idx2 = tid; idx2 < 1024; idx2 += 192) {
            int mm = idx2 >> 4, n = idx2 & 15;
            int jj = s * 64 + t * 16 + n;
            bool ok = jj < NH;
            float pi = tile[0][mm][n] + (ok ? b_iou[jj] : 0.f);
            float po = tile[1][mm][n] + (ok ? b_iou[NH + jj] : 0.f);
            float pu = tile[2][mm][n] + (ok ? b_iou[2 * NH + jj] : 0.f);
            float cc = sigmoidf_(pi) * tanhf(pu);
            float hh = sigmoidf_(po) * tanhf(cc);
            size_t tbase = ((size_t)p * 10 + (jj >> 5)) * TS + swz(mm, jj & 31);
            if (ok) Cg[tbase] = f2h(cc);
            HbfT[tbase] = ok ? f2bf(hh) : (unsigned short)0;
        }
    }
}

// fence-free tail barrier (R11-proven visibility chain): sc1 stores retired
// by the __syncthreads vmcnt drain; relaxed agent counter; plain reads after.
__device__ __forceinline__ void tbar(int* c, int tid) {
    __syncthreads();
    if (tid == 0) {
        __hip_atomic_fetch_add(c, 1, __ATOMIC_RELAXED, __HIP_MEMORY_SCOPE_AGENT);
        while (__hip_atomic_load(c, __ATOMIC_RELAXED, __HIP_MEMORY_SCOPE_AGENT) < 160)
            __builtin_amdgcn_s_sleep(2);
    }
    __syncthreads();
}

// ---------------- merged tail: levels 4..0 + out, 160 blocks ----------------
__global__ __launch_bounds__(320) void tail_kernel(
    const int* __restrict__ x, const float* __restrict__ embed,
    const unsigned short* __restrict__ BW,
    const float* __restrict__ b_iou, const float* __restrict__ b_f,
    const float* __restrict__ W_out, const float* __restrict__ b_out,
    unsigned short* __restrict__ HbfT, unsigned short* __restrict__ Cg,
    float* __restrict__ out, int* __restrict__ bar)
{
    __shared__ unsigned short sm[24 * HTS];   // 48 KB
    int bid = blockIdx.x, tid = threadIdx.x;

    {   // d=4: 16 nodes x 10 = 160 tasks (children from level-5 dispatch)
        int p = 15 + (bid & 15), rest = bid >> 4;
        internal_body(sm, p, rest % 5, rest / 5, tid, x, embed, BW, b_iou, b_f, HbfT, Cg, 1);
    }
    tbar(bar + 0, tid);
    if (bid < 80) {   // d=3
        int p = 7 + (bid & 7), rest = bid >> 3;
        internal_body(sm, p, rest % 5, rest / 5, tid, x, embed, BW, b_iou, b_f, HbfT, Cg, 1);
    }
    tbar(bar + 1, tid);
    if (bid < 40) {   // d=2
        int p = 3 + (bid & 3), rest = bid >> 2;
        internal_body(sm, p, rest % 5, rest / 5, tid, x, embed, BW, b_iou, b_f, HbfT, Cg, 1);
    }
    tbar(bar + 2, tid);
    if (bid < 20) {   // d=1
        int p = 1 + (bid & 1), rest = bid >> 1;
        internal_body(sm, p, rest % 5, rest / 5, tid, x, embed, BW, b_iou, b_f, HbfT, Cg, 1);
    }
    tbar(bar + 3, tid);
    if (bid < 10) {   // d=0 (root)
        internal_body(sm, 0, bid % 5, bid / 5, tid, x, embed, BW, b_iou, b_f, HbfT, Cg, 1);
    }
    tbar(bar + 4, tid);

    if (bid == 0 && tid < NB) {
        int b = tid;
        float l0 = 0.f, l1 = 0.f;
#pragma unroll 4
        for (int k = 0; k < NH; ++k) {
            float hk = bf2f(HbfT[(size_t)(k >> 5) * TS + swz(b, k & 31)]);
            l0 += hk * W_out[k * 2];
            l1 += hk * W_out[k * 2 + 1];
        }
        l0 += b_out[0];
        l1 += b_out[1];
        float mx = fmaxf(l0, l1);
        float lse = mx + logf(__expf(l0 - mx) + __expf(l1 - mx));
        out[b * 2 + 0] = l0 - lse;
        out[b * 2 + 1] = l1 - lse;
    }
}

extern "C" void kernel_launch(void* const* d_in, const int* in_sizes, int n_in,
                              void* d_out, int out_size, void* d_ws, size_t ws_size,
                              hipStream_t stream)
{
    const int*   x     = (const int*)d_in[0];
    const float* embed = (const float*)d_in[3];
    const float* W_iou = (const float*)d_in[4];
    const float* U_iou = (const float*)d_in[5];
    const float* b_iou = (const float*)d_in[6];
    const float* W_f   = (const float*)d_in[7];
    const float* U_f   = (const float*)d_in[8];
    const float* b_f   = (const float*)d_in[9];
    const float* W_out = (const float*)d_in[10];
    const float* b_out = (const float*)d_in[11];

    char* ws = (char*)d_ws;
    unsigned short* HbfT = (unsigned short*)(ws + 0);
    unsigned short* Cg   = (unsigned short*)(ws + 10444800);
    unsigned short* BW   = (unsigned short*)(ws + 28200960);
    int*            bar  = (int*)(ws + 29593600);

    hipMemsetAsync(bar, 0, 64, stream);
    prep_kernel<<<340, 256, 0, stream>>>(U_iou, U_f, W_iou, W_f, BW);
    // leaf d=7: 128 nodes x 5 strips
    leaf_kernel<<<640, 192, 0, stream>>>(x, embed, BW, b_iou, HbfT, Cg);
    // d=6 (64 nodes), d=5 (32 nodes): 10 tasks/node
    level_kernel<<<640, 320, 0, stream>>>(x, embed, BW, b_iou, b_f, HbfT, Cg, 63, 8);
    level_kernel<<<320, 320, 0, stream>>>(x, embed, BW, b_iou, b_f, HbfT, Cg, 31, 4);
    // d=4..0 + out merged
    tail_kernel<<<160, 320, 0, stream>>>(x, embed, BW, b_iou, b_f, W_out, b_out,
                                         HbfT, Cg, (float*)d_out, bar);
}